// Round 8
// baseline (387.310 us; speedup 1.0000x reference)
//
#include <hip/hip_runtime.h>

// CRF Viterbi forward decode — R10: R6 skeleton + hazard-split scan +
// offset-immediate addressing + pk-add-friendly float2 candidates.
// potentials: [1024, 512, 48] f32, transition: [48, 48] f32.
// out = backpointers [1024, 511, 48] (float-encoded) ++ scores [1024, 48] f32.
//
// Measured ladder: R6 fused+shadow = 205 us dispatch (BEST). R8 in-step
// argmax 228. R9 readlane broadcast 246 (900 busy cyc/step: readlane +
// SGPR hazards beat the LDS roundtrip they replaced). R7 4-wave split 414.
// R5 two-phase 386. Conclusion: keep R6's structure; attack the ~2x busy
// inflation (hazards + addressing) without touching what works.
//
// Changes vs R6 (each bit-identical in arithmetic):
//  1. Shadow scan split into FOUR independent 12-deep backward chains
//     (xx0..xx3, separate compare dests) + min3 combine. Same first-
//     occurrence result; chains interleave so the 47 serial vcc
//     write->read hazards no longer stack up.
//  2. bp stores use offset-immediates from a chunk-walking base (bpc);
//     prefetch uses a walking pld pointer with offset-immediates.
//     Kills per-step 64-bit pointer adds + per-load clamp math (R9-
//     validated addressing, minus R9's readlane mistake).
//  3. tcol/cand held as float2 pairs -> compiler can emit v_pk_add_f32
//     (48 -> 24 add insts). Values identical.
//
// Block = 1 wave, 48 lanes, lane j = destination tag; 1 block per batch.
// wave_barrier = scheduling fence only (single-wave workgroup, in-order
// DS pipe — absmax 0 across R2-R9). No vmcnt-draining barriers.

constexpr int B_ = 1024;
constexpr int T_ = 512;
constexpr int K_ = 48;
constexpr int C_ = 6;   // steps t=2..511 -> 510 = 6 * 85, no remainder

__device__ __forceinline__ int min3i(int a, int b, int c) {
    int m = a < b ? a : b;
    return m < c ? m : c;   // -> v_min3_i32
}

// Compile-time component accessor for float2-paired candidate arrays.
#define C2(A, i) ((i) & 1 ? A[(i) >> 1].y : A[(i) >> 1].x)

__global__ __launch_bounds__(64, 1) void crf_viterbi_kernel(
    const float* __restrict__ pot,
    const float* __restrict__ trans,
    float* __restrict__ out)
{
    const int b = blockIdx.x;
    const int j = threadIdx.x;  // 0..47 = destination tag

    __shared__ __align__(16) float stv[K_];  // wave-synchronous state buffer

    // Transition column j as float2 pairs (reused 511 times).
    float2 tcol2[K_ / 2];
    #pragma unroll
    for (int i = 0; i < K_ / 2; ++i)
        tcol2[i] = make_float2(trans[(2 * i) * K_ + j],
                               trans[(2 * i + 1) * K_ + j]);

    const float* pp = pot + (size_t)b * T_ * K_ + j;
    float* bpc      = out + (size_t)b * (T_ - 1) * K_ + j;   // chunk-walking bp base (row 0)
    float* scout    = out + (size_t)B_ * (T_ - 1) * K_ + (size_t)b * K_ + j;

    // t = 0 state.
    float myst = pp[0];
    stv[j] = myst;
    __builtin_amdgcn_wave_barrier();

    // Parity-double-buffered candidates + exact max (shadow reads the buffer
    // the PREVIOUS step wrote; no register copies).
    float2 candA2[K_ / 2], candB2[K_ / 2];
    float mmA = 0.0f, mmB = 0.0f;

    // Rotating bp store-data registers (redefined 6 steps after their store
    // -> no per-step vmcnt store-ack WAR stall).
    float bpf0 = 0.0f, bpf1 = 0.0f, bpf2 = 0.0f,
          bpf3 = 0.0f, bpf4 = 0.0f, bpf5 = 0.0f;

// 4-way-split backward first-occurrence scan: four independent 12-deep
// chains (hazards interleave), min3-combined. Result = smallest matching
// index = first occurrence (63 sentinel loses to any match).
#define SCAN4(CO2, MMO, XXDST)                                                 \
    do {                                                                       \
        int xx0 = 63, xx1 = 63, xx2 = 63, xx3 = 63;                            \
        _Pragma("unroll")                                                      \
        for (int i = 11; i >= 0; --i)  xx0 = (C2(CO2, i) == (MMO)) ? i : xx0;  \
        _Pragma("unroll")                                                      \
        for (int i = 23; i >= 12; --i) xx1 = (C2(CO2, i) == (MMO)) ? i : xx1;  \
        _Pragma("unroll")                                                      \
        for (int i = 35; i >= 24; --i) xx2 = (C2(CO2, i) == (MMO)) ? i : xx2;  \
        _Pragma("unroll")                                                      \
        for (int i = 47; i >= 36; --i) xx3 = (C2(CO2, i) == (MMO)) ? i : xx3;  \
        XXDST = min3i(xx0, xx1, xx2) < xx3 ? min3i(xx0, xx1, xx2) : xx3;       \
    } while (0)

// One step. CN2/MMN: written this step; CO2/MMO: previous step's (shadow
// input). UOFF: compile-time row offset from bpc for the shadow store.
#define STEP(PCUR, CN2, CO2, MMN, MMO, DOSH, UOFF, BPV)                        \
    do {                                                                       \
        /* (1) Batched broadcast reads — 12 x ds_read_b128, static offsets. */ \
        float4 sv[12];                                                         \
        const float4* stv4 = (const float4*)stv;                               \
        _Pragma("unroll")                                                      \
        for (int c = 0; c < 12; ++c) sv[c] = stv4[c];                          \
        /* (2) Shadow: previous step's argmax + bp store (fills LDS window) */ \
        if (DOSH) {                                                            \
            int xx;                                                            \
            SCAN4(CO2, MMO, xx);                                               \
            BPV = (float)xx;                                                   \
            bpc[(UOFF) * K_] = BPV;   /* offset-immediate store */             \
        }                                                                      \
        /* (3) 48 candidates as float2 pairs (pk-add candidates). */           \
        _Pragma("unroll")                                                      \
        for (int c = 0; c < 12; ++c) {                                         \
            CN2[2 * c]     = make_float2(sv[c].x + tcol2[2 * c].x,             \
                                         sv[c].y + tcol2[2 * c].y);            \
            CN2[2 * c + 1] = make_float2(sv[c].z + tcol2[2 * c + 1].x,         \
                                         sv[c].w + tcol2[2 * c + 1].y);        \
        }                                                                      \
        /* (4) Ternary value tree -> v_max3_f32: 16+5+2+1 = 24 ops, depth 4.*/ \
        float m1[16];                                                          \
        _Pragma("unroll")                                                      \
        for (int k = 0; k < 16; ++k)                                           \
            m1[k] = fmaxf(fmaxf(C2(CN2, 3 * k), C2(CN2, 3 * k + 1)),           \
                          C2(CN2, 3 * k + 2));                                 \
        float m2[6];                                                           \
        _Pragma("unroll")                                                      \
        for (int k = 0; k < 5; ++k)                                            \
            m2[k] = fmaxf(fmaxf(m1[3 * k], m1[3 * k + 1]), m1[3 * k + 2]);     \
        m2[5] = m1[15];                                                        \
        float mm = fmaxf(fmaxf(fmaxf(m2[0], m2[1]), m2[2]),                    \
                         fmaxf(fmaxf(m2[3], m2[4]), m2[5]));                   \
        MMN = mm;                                                              \
        /* (5) New state -> LDS; fence orders write(t) before reads(t+1). */   \
        myst = (PCUR) + mm;                                                    \
        stv[j] = myst;                                                         \
        __builtin_amdgcn_wave_barrier();                                       \
    } while (0)

    // Potential for t=1 and prefetch t=2..7.
    float p1 = pp[(size_t)1 * K_];
    float pbuf[C_];
    #pragma unroll
    for (int u = 0; u < C_; ++u) pbuf[u] = pp[(size_t)(2 + u) * K_];
    const float* pld = pp + (size_t)8 * K_;   // next prefetch target (t=8)

    // t = 1 (odd): writes candB2; no shadow yet.
    STEP(p1, candB2, candA2, mmB, mmA, false, 0, bpf0);

    for (int t0 = 2; t0 < T_; t0 += C_) {   // t0 = 2, 8, ..., 506 (85 chunks)
        float pc[C_];
        #pragma unroll
        for (int u = 0; u < C_; ++u) pc[u] = pbuf[u];

        // Prefetch t0+6..t0+11 via walking pointer + offset-immediates;
        // uniform guard skips the OOB final-chunk prefetch.
        if (t0 < T_ - C_) {
            #pragma unroll
            for (int u = 0; u < C_; ++u) pbuf[u] = pld[(size_t)u * K_];
            pld += (size_t)C_ * K_;
        }

        // Steps t0..t0+5; shadows store bp rows t0-2..t0+3 at offsets 0..5.
        STEP(pc[0], candA2, candB2, mmA, mmB, true, 0, bpf0);
        STEP(pc[1], candB2, candA2, mmB, mmA, true, 1, bpf1);
        STEP(pc[2], candA2, candB2, mmA, mmB, true, 2, bpf2);
        STEP(pc[3], candB2, candA2, mmB, mmA, true, 3, bpf3);
        STEP(pc[4], candA2, candB2, mmA, mmB, true, 4, bpf4);
        STEP(pc[5], candB2, candA2, mmB, mmA, true, 5, bpf5);
        bpc += (size_t)C_ * K_;
    }

    // Final shadow: argmax for t = 511 (odd -> candB2/mmB) -> bp row 510.
    {
        int xx;
        SCAN4(candB2, mmB, xx);
        bpc[0] = (float)xx;
    }

    // Keep rotating store regs live (defeat DSE of the rotation).
    asm volatile("" :: "v"(bpf0), "v"(bpf1), "v"(bpf2),
                       "v"(bpf3), "v"(bpf4), "v"(bpf5));

    // Final Viterbi scores (S(511)).
    *scout = myst;
#undef STEP
#undef SCAN4
#undef C2
}

extern "C" void kernel_launch(void* const* d_in, const int* in_sizes, int n_in,
                              void* d_out, int out_size, void* d_ws, size_t ws_size,
                              hipStream_t stream) {
    const float* pot   = (const float*)d_in[0];
    const float* trans = (const float*)d_in[1];
    float* out         = (float*)d_out;
    crf_viterbi_kernel<<<dim3(B_), dim3(K_), 0, stream>>>(pot, trans, out);
}

// Round 17
// 333.323 us; speedup vs baseline: 1.1620x; 1.1620x over previous
//
#include <hip/hip_runtime.h>

// CRF Viterbi forward decode — R11 (8th resubmit; 7x GPU-acquisition
// timeout + 1x container failure, never measured): R6 skeleton +
// single-pass fused (value,index) tournament. ONE lever vs R6.
// potentials: [1024, 512, 48] f32, transition: [48, 48] f32.
// out = backpointers [1024, 511, 48] (float-encoded) ++ scores [1024, 48] f32.
//
// Ladder (dispatch us): R6 fused+shadow 205 (best), R8 228, R9 246,
// R10 278, R7 414. Busy-cycle ledger shows every variant's busy is ~2x its
// source-level inst model, with anomalously low VGPR (64-108) vs live-set
// estimates: the allocator refuses residency and RECOMPUTES. R6/R8/R9 all
// read cand[48] twice (max tree, then eq-scan) -> ~48 recomputed adds +
// copies ~= the missing ~280 busy cyc/step.
//
// R11 fix: fused tournament, 47 merges of (value,index):
//     vd = fmaxf(va,vb); xd = (va>=vb) ? xa : xb
// 3 VALU/merge (max + cmp + cndmask; leaf indices are VOP3 inline consts).
// Each cand consumed by exactly ONE merge -> no second pass, no recompute,
// no cross-step cand liveness; candA/B + mmA/mmB die. Exact: fp max is
// associative; >= with left-priority at every merge = min index among
// maxima = first-occurrence (jnp.argmax semantics). bp row t-1 stored
// in-step; mm -> myst -> ds_write emitted before the bp cvt/store so the
// value recurrence stays the critical path.
//
// Probe-observability note: harness top-5 counter rows = 5 instances of
// the SLOWEST kernel in the launch -> multi-kernel ablation probes are
// near-blind; contingency is 2-kernel rounds (probe + known-good full
// kernel; probe inferred via headline-overhead subtraction, ~100+-10 us).
//
// Block = 1 wave, 48 lanes, lane j = destination tag; 1 block per batch.
// wave_barrier = scheduling fence only (single-wave workgroup, in-order DS
// pipe — absmax 0 across R2-R10). No vmcnt-draining barriers anywhere.

constexpr int B_ = 1024;
constexpr int T_ = 512;
constexpr int K_ = 48;
constexpr int C_ = 6;   // steps t=2..511 -> 510 = 6 * 85, no remainder

__global__ __launch_bounds__(64, 1)
__attribute__((amdgpu_waves_per_eu(1, 1)))
void crf_viterbi_kernel(
    const float* __restrict__ pot,
    const float* __restrict__ trans,
    float* __restrict__ out)
{
    const int b = blockIdx.x;
    const int j = threadIdx.x;  // 0..47 = destination tag

    __shared__ __align__(16) float stv[K_];  // wave-synchronous state buffer

    // Transition column j -> 48 VGPRs (reused 511 times).
    float tcol[K_];
    #pragma unroll
    for (int i = 0; i < K_; ++i) tcol[i] = trans[i * K_ + j];

    const float* pp = pot + (size_t)b * T_ * K_ + j;
    float* bpp      = out + (size_t)b * (T_ - 1) * K_ + j;   // walking bp ptr
    float* scout    = out + (size_t)B_ * (T_ - 1) * K_ + (size_t)b * K_ + j;

    // t = 0 state.
    float myst = pp[0];
    stv[j] = myst;
    __builtin_amdgcn_wave_barrier();

    // Rotating bp store-data registers: slot u redefined only 6 steps after
    // its store -> no per-step vmcnt store-ack WAR stall.
    float bpf0 = 0.0f, bpf1 = 0.0f, bpf2 = 0.0f,
          bpf3 = 0.0f, bpf4 = 0.0f, bpf5 = 0.0f;

// One merge of the (value,index) tournament. Left wins ties (>=) ->
// first-occurrence argmax. max + cmp independent; cndmask depends on cmp.
#define MRG(VD, XD, VA, XA, VB, XB)                                            \
    do {                                                                       \
        bool c_ = (VA) >= (VB);                                                \
        VD = fmaxf((VA), (VB));                                                \
        XD = c_ ? (XA) : (XB);                                                 \
    } while (0)

// One step t (t=1..511): ds_read S(t-1) -> cand -> fused tournament
// (mm, xx in one pass) -> myst -> ds_write -> bp row (t-1) store -> fence.
#define STEP(PCUR, BPV)                                                        \
    do {                                                                       \
        /* (1) Batched broadcast reads — 12 x ds_read_b128, static offsets. */ \
        float4 sv[12];                                                         \
        const float4* stv4 = (const float4*)stv;                               \
        _Pragma("unroll")                                                      \
        for (int c = 0; c < 12; ++c) sv[c] = stv4[c];                          \
        /* (2) 48 candidates (each consumed once, by its leaf merge). */       \
        float cand[K_];                                                        \
        _Pragma("unroll")                                                      \
        for (int c = 0; c < 12; ++c) {                                         \
            cand[4 * c + 0] = sv[c].x + tcol[4 * c + 0];                       \
            cand[4 * c + 1] = sv[c].y + tcol[4 * c + 1];                       \
            cand[4 * c + 2] = sv[c].z + tcol[4 * c + 2];                       \
            cand[4 * c + 3] = sv[c].w + tcol[4 * c + 3];                       \
        }                                                                      \
        /* (3) Fused tournament: 47 merges, depth 6, single pass. Leaf        \
           indices 2k/2k+1 are VOP3 inline constants (<= 47 < 64). */          \
        float v1[24]; int x1[24];                                              \
        _Pragma("unroll")                                                      \
        for (int k = 0; k < 24; ++k)                                           \
            MRG(v1[k], x1[k], cand[2 * k], 2 * k, cand[2 * k + 1], 2 * k + 1); \
        float v2[12]; int x2[12];                                              \
        _Pragma("unroll")                                                      \
        for (int k = 0; k < 12; ++k)                                           \
            MRG(v2[k], x2[k], v1[2 * k], x1[2 * k], v1[2 * k + 1], x1[2 * k + 1]); \
        float v3[6]; int x3[6];                                                \
        _Pragma("unroll")                                                      \
        for (int k = 0; k < 6; ++k)                                            \
            MRG(v3[k], x3[k], v2[2 * k], x2[2 * k], v2[2 * k + 1], x2[2 * k + 1]); \
        float v4[3]; int x4[3];                                                \
        _Pragma("unroll")                                                      \
        for (int k = 0; k < 3; ++k)                                            \
            MRG(v4[k], x4[k], v3[2 * k], x3[2 * k], v3[2 * k + 1], x3[2 * k + 1]); \
        float v5; int x5;                                                      \
        MRG(v5, x5, v4[0], x4[0], v4[1], x4[1]);                               \
        float mm; int xx;                                                      \
        MRG(mm, xx, v5, x5, v4[2], x4[2]);                                     \
        /* (4) Value recurrence first (critical path), then bp store. */       \
        myst = (PCUR) + mm;                                                    \
        stv[j] = myst;                                                         \
        BPV = (float)xx;                                                       \
        *bpp = BPV;            /* bp row t-1 */                                \
        bpp += K_;                                                             \
        __builtin_amdgcn_wave_barrier();                                       \
    } while (0)

    // Potential for t=1 and prefetch t=2..7 (R6's measured-good clamp form).
    float p1 = pp[(size_t)1 * K_];
    float pbuf[C_];
    #pragma unroll
    for (int u = 0; u < C_; ++u) pbuf[u] = pp[(size_t)(2 + u) * K_];

    // t = 1: stores bp row 0.
    STEP(p1, bpf5);

    for (int t0 = 2; t0 < T_; t0 += C_) {   // t0 = 2, 8, ..., 506 (85 chunks)
        float pc[C_];
        #pragma unroll
        for (int u = 0; u < C_; ++u) pc[u] = pbuf[u];

        // Prefetch next chunk (clamped; dup loads harmless; 6-step slack,
        // no vmcnt-draining barriers to expose the latency).
        #pragma unroll
        for (int u = 0; u < C_; ++u) {
            int tn = t0 + C_ + u;
            if (tn > T_ - 1) tn = T_ - 1;
            pbuf[u] = pp[(size_t)tn * K_];
        }

        STEP(pc[0], bpf0);
        STEP(pc[1], bpf1);
        STEP(pc[2], bpf2);
        STEP(pc[3], bpf3);
        STEP(pc[4], bpf4);
        STEP(pc[5], bpf5);
    }

    // Keep rotating store regs live (defeat DSE of the rotation).
    asm volatile("" :: "v"(bpf0), "v"(bpf1), "v"(bpf2),
                       "v"(bpf3), "v"(bpf4), "v"(bpf5));

    // Final Viterbi scores (S(511)).
    *scout = myst;
#undef STEP
#undef MRG
}

extern "C" void kernel_launch(void* const* d_in, const int* in_sizes, int n_in,
                              void* d_out, int out_size, void* d_ws, size_t ws_size,
                              hipStream_t stream) {
    const float* pot   = (const float*)d_in[0];
    const float* trans = (const float*)d_in[1];
    float* out         = (float*)d_out;
    crf_viterbi_kernel<<<dim3(B_), dim3(K_), 0, stream>>>(pot, trans, out);
}